// Round 6
// baseline (722.996 us; speedup 1.0000x reference)
//
#include <hip/hip_runtime.h>

typedef __bf16 bf16_t;
typedef __bf16 bf16x8 __attribute__((ext_vector_type(8)));
typedef float  f32x4  __attribute__((ext_vector_type(4)));
typedef unsigned int u32x4 __attribute__((ext_vector_type(4)));

#define T_STEPS 512
#define BATCH   2048
#define NS      64
#define FSTR    36

#define K_SIG  (-1.4426950408889634f)   // sigmoid: s = rcp(1+exp2(K_SIG*pre))
#define K_TANH ( 2.8853900817779268f)   // tanh:    t = 1-2*rcp(1+exp2(K_TANH*pre))

#define MFMA(A, B, C) __builtin_amdgcn_mfma_f32_16x16x32_bf16((A), (B), (C), 0, 0, 0)

// lgkm-only barrier: global x-prefetch loads stay in flight across it
__device__ __forceinline__ void barrier_lgkm() {
  asm volatile("s_waitcnt lgkmcnt(0)\n\ts_barrier" ::: "memory");
}

// 8-wave cooperative LSTM chain: 16 batch rows x 32 hidden units per block.
// The recurrence is bound by transcendental issue (~80 trans wave-instrs/CU/step
// in all prior variants => ~1280cy/step). Two attacks:
//  (1) shared-reciprocal pairing: 1/(1+A),1/(1+B) from ONE rcp of the product
//      => 10 -> 8 trans per cell;
//  (2) 8 waves, ONE cell per lane per wave, 2 waves/SIMD: co-resident wave
//      issues through the other's stalls (first variant with >1 wave/SIMD).
// Sibling waves duplicate MFMA/x work (idle pipes; L1 absorbs dup loads).
// h exchange: 1 ds_write_b16 + 4 ds_read_b32 per lane, double-buffered,
// one barrier/step. W_hh contraction order permuted so MFMA C/D h-layout ==
// next step's B-frag layout (slot 8q+j <-> unit j<4 ? 4q+j : 16+4q+j-4).
__global__ __launch_bounds__(512, 2)
void lstm_policy_kernel(const float* __restrict__ x,
                        const float* __restrict__ W_ih,
                        const float* __restrict__ W_hh,
                        const float* __restrict__ b_ih,
                        const float* __restrict__ b_hh,
                        const float* __restrict__ W_d,
                        const float* __restrict__ b_d,
                        float* __restrict__ out)
{
  __shared__ unsigned int hlds[2][4][64];  // [parity][pp][lane]: 2xbf16 packed
  __shared__ float hf[16 * FSTR];          // final relu(h) for dense epilogue

  const int tid  = threadIdx.x;
  const int wv   = tid >> 6;               // 0..7
  const int lane = tid & 63;
  const int m    = lane & 15;              // batch row within tile (B-col)
  const int q    = lane >> 4;              // 0..3
  const int U    = wv >> 2;                // unit-tile (0 or 1)
  const int r3   = wv & 3;                 // which cell r of the f32x4 this wave owns
  const int row0 = blockIdx.x << 4;        // global batch row base

  // ---- preload W frags for our U, pre-scaled by activation input constants ----
  bf16x8 a_ih[4][2], a_hh[4];
  f32x4  bias[4];
  #pragma unroll
  for (int G = 0; G < 4; ++G) {
    const float k = (G == 2) ? K_TANH : K_SIG;
    const int wrow = (G << 5) + (U << 4) + m;      // gate-major row of 4H=128
    const float* pih = W_ih + wrow * 64;
    const float* phh = W_hh + (wrow << 5);
    #pragma unroll
    for (int j = 0; j < 8; ++j) {
      a_ih[G][0][j] = (bf16_t)(k * pih[(q << 3) + j]);
      a_ih[G][1][j] = (bf16_t)(k * pih[32 + (q << 3) + j]);
      const int us = (j < 4) ? ((q << 2) + j) : (16 + (q << 2) + (j - 4));
      a_hh[G][j] = (bf16_t)(k * phh[us]);          // permuted contraction order
    }
    #pragma unroll
    for (int r = 0; r < 4; ++r) {
      const int u = (G << 5) + (U << 4) + (q << 2) + r;
      bias[G][r] = (b_ih[u] + b_hh[u]) * k;
    }
  }

  const size_t xstep = (size_t)BATCH * NS;         // 1<<17 floats per timestep
  const float* xb = x + (size_t)row0 * NS;         // wave-uniform base
  const int    lo = m * NS + (q << 3);             // per-lane invariant offset

  // ---- x ring: slot s holds x[t], t%4==s (prologue: s1=x1,s2=x2,s3=x3,s0=x4) ----
  f32x4 xf[4][4];
  {
    const float* p1 = xb + 1 * xstep + lo;
    const float* p2 = xb + 2 * xstep + lo;
    const float* p3 = xb + 3 * xstep + lo;
    const float* p4 = xb + 4 * xstep + lo;
    xf[1][0]=*(const f32x4*)(p1); xf[1][1]=*(const f32x4*)(p1+4); xf[1][2]=*(const f32x4*)(p1+32); xf[1][3]=*(const f32x4*)(p1+36);
    xf[2][0]=*(const f32x4*)(p2); xf[2][1]=*(const f32x4*)(p2+4); xf[2][2]=*(const f32x4*)(p2+32); xf[2][3]=*(const f32x4*)(p2+36);
    xf[3][0]=*(const f32x4*)(p3); xf[3][1]=*(const f32x4*)(p3+4); xf[3][2]=*(const f32x4*)(p3+32); xf[3][3]=*(const f32x4*)(p3+36);
    xf[0][0]=*(const f32x4*)(p4); xf[0][1]=*(const f32x4*)(p4+4); xf[0][2]=*(const f32x4*)(p4+32); xf[0][3]=*(const f32x4*)(p4+36);
  }

  // ---- acc[G]: gate pre-activations for our U at t=0 (x-part + bias) ----
  f32x4 acc[4];
  {
    const float* p0 = xb + lo;
    f32x4 x0a = *(const f32x4*)(p0),      x0b = *(const f32x4*)(p0 + 4);
    f32x4 x0c = *(const f32x4*)(p0 + 32), x0d = *(const f32x4*)(p0 + 36);
    bf16x8 xA, xB;
    #pragma unroll
    for (int j = 0; j < 4; ++j) {
      xA[j] = (bf16_t)x0a[j]; xA[4+j] = (bf16_t)x0b[j];
      xB[j] = (bf16_t)x0c[j]; xB[4+j] = (bf16_t)x0d[j];
    }
    #pragma unroll
    for (int G = 0; G < 4; ++G) {
      acc[G] = MFMA(a_ih[G][0], xA, bias[G]);
      acc[G] = MFMA(a_ih[G][1], xB, acc[G]);
    }
  }

  float  cst = 0.0f;   // c-state for THE cell this wave owns (K_TANH basis)
  bf16x8 hB  = {};     // full h B-frag (h_{-1}=0), rebuilt each step

  // One cell, literal index RR. Shared-rcp pairing: 1/(1+A),1/(1+B) via
  // r=rcp((1+A)(1+B)); then fma(B,r,r) / fma(A,r,r). 8 trans (was 10).
  #define CELLX(RR)                                                                 \
    {                                                                               \
      const float Ai = __builtin_amdgcn_exp2f(gr[0][RR]);                           \
      const float Af = __builtin_amdgcn_exp2f(gr[1][RR]);                           \
      const float Ag = __builtin_amdgcn_exp2f(gr[2][RR]);                           \
      const float Ao = __builtin_amdgcn_exp2f(gr[3][RR]);                           \
      const float rif = __builtin_amdgcn_rcpf(                                      \
          __builtin_fmaf(Ai, Af, Ai + Af) + 1.0f);                                  \
      const float iv = __builtin_fmaf(Af, rif, rif);   /* 1/(1+Ai) */               \
      const float fv = __builtin_fmaf(Ai, rif, rif);   /* 1/(1+Af) */               \
      const float rgo = __builtin_amdgcn_rcpf(                                      \
          __builtin_fmaf(Ag, Ao, Ag + Ao) + 1.0f);                                  \
      const float rg = __builtin_fmaf(Ao, rgo, rgo);   /* 1/(1+Ag) */               \
      const float ov = __builtin_fmaf(Ag, rgo, rgo);   /* 1/(1+Ao) */               \
      const float gs = __builtin_fmaf(-2.0f * K_TANH, rg, K_TANH); /* K*tanh(g) */  \
      const float cn = __builtin_fmaf(fv, cst, iv * gs);           /* K*c_new  */   \
      cst = cn;                                                                     \
      const float rh  = __builtin_amdgcn_rcpf(1.0f + __builtin_amdgcn_exp2f(cn));   \
      const float ov2 = ov + ov;                                                    \
      const float h   = __builtin_fmaf(-ov2, rh, ov);              /* o*tanh(c) */  \
      const unsigned short hs =                                                     \
          __builtin_bit_cast(unsigned short, (bf16_t)h);                            \
      ((unsigned short*)&hlds[par][(U << 1) | ((RR) >> 1)][lane])[(RR) & 1] = hs;   \
      if (tt == T_STEPS - 1)                                                        \
        hf[m * FSTR + (U << 4) + (q << 2) + (RR)] = fmaxf(h, 0.0f);                 \
    }

  // STEP(P): gr-MFMA -> own-cell activation + b16 publish -> barrier ->
  //          4 h-reads; x-part MFMAs for t+1 fill the ds_read latency -> hB.
  #define STEP(P)                                                                   \
  do {                                                                              \
    const int tt  = t + (P);                                                        \
    const int par = (P) & 1;                                                        \
    f32x4 gr[4];                                                                    \
    _Pragma("unroll")                                                               \
    for (int G = 0; G < 4; ++G)                                                     \
      gr[G] = MFMA(a_hh[G], hB, acc[G]);                                            \
    if      (r3 == 0) CELLX(0)                                                      \
    else if (r3 == 1) CELLX(1)                                                      \
    else if (r3 == 2) CELLX(2)                                                      \
    else              CELLX(3)                                                      \
    barrier_lgkm();                                                                 \
    const unsigned int w0 = hlds[par][0][lane];                                     \
    const unsigned int w1 = hlds[par][1][lane];                                     \
    const unsigned int w2 = hlds[par][2][lane];                                     \
    const unsigned int w3 = hlds[par][3][lane];                                     \
    /* x-part for t+1 overwrites acc (WAR); hides ds_read latency */                \
    {                                                                               \
      const int ns = ((P) + 1) & 3;                                                 \
      bf16x8 xA, xB;                                                                \
      _Pragma("unroll")                                                             \
      for (int j = 0; j < 4; ++j) {                                                 \
        xA[j] = (bf16_t)xf[ns][0][j]; xA[4+j] = (bf16_t)xf[ns][1][j];               \
        xB[j] = (bf16_t)xf[ns][2][j]; xB[4+j] = (bf16_t)xf[ns][3][j];               \
      }                                                                             \
      _Pragma("unroll")                                                             \
      for (int G = 0; G < 4; ++G) {                                                 \
        acc[G] = MFMA(a_ih[G][0], xA, bias[G]);                                     \
        acc[G] = MFMA(a_ih[G][1], xB, acc[G]);                                      \
      }                                                                             \
      int tp = tt + 5; if (tp > T_STEPS - 1) tp = T_STEPS - 1;                      \
      const float* pf = xb + (size_t)tp * xstep + lo;                               \
      xf[ns][0] = *(const f32x4*)(pf);                                              \
      xf[ns][1] = *(const f32x4*)(pf + 4);                                          \
      xf[ns][2] = *(const f32x4*)(pf + 32);                                         \
      xf[ns][3] = *(const f32x4*)(pf + 36);                                         \
    }                                                                               \
    {                                                                               \
      u32x4 hw; hw[0] = w0; hw[1] = w1; hw[2] = w2; hw[3] = w3;                     \
      hB = __builtin_bit_cast(bf16x8, hw);                                          \
    }                                                                               \
  } while (0)

  #pragma unroll 1
  for (int t = 0; t < T_STEPS; t += 4) {
    STEP(0);
    STEP(1);
    STEP(2);
    STEP(3);
  }
  #undef STEP
  #undef CELLX

  __syncthreads();

  // dense epilogue: out[row][a] = relu(h_T[row]) . W_d[a] + b_d[a]
  if (tid < 48) {
    const int r = tid / 3;
    const int a = tid - r * 3;
    float s = b_d[a];
    #pragma unroll
    for (int u = 0; u < 32; ++u)
      s += hf[r * FSTR + u] * W_d[a * 32 + u];
    out[(size_t)(row0 + r) * 3 + a] = s;
  }
}

extern "C" void kernel_launch(void* const* d_in, const int* in_sizes, int n_in,
                              void* d_out, int out_size, void* d_ws, size_t ws_size,
                              hipStream_t stream) {
  const float* x    = (const float*)d_in[0];
  const float* W_ih = (const float*)d_in[1];
  const float* W_hh = (const float*)d_in[2];
  const float* b_ih = (const float*)d_in[3];
  const float* b_hh = (const float*)d_in[4];
  const float* W_d  = (const float*)d_in[5];
  const float* b_d  = (const float*)d_in[6];
  float* out = (float*)d_out;

  dim3 grid(BATCH / 16);   // 128 chains, one per block
  dim3 block(512);         // 8 waves: 1 cell/lane/wave, 2 waves/SIMD
  hipLaunchKernelGGL(lstm_policy_kernel, grid, block, 0, stream,
                     x, W_ih, W_hh, b_ih, b_hh, W_d, b_d, out);
}